// Round 10
// baseline (575.447 us; speedup 1.0000x reference)
//
#include <hip/hip_runtime.h>

#define D 32
#define NPB 64                      // nodes per fused block (dst-local fits 6 bits)
#define SRC_BITS 25
#define SRC_MASK ((1 << SRC_BITS) - 1)
#define SCAN_CHUNK 1024
#define PKCAP 2048                  // staged srcpk per block (mean EB=1024)

typedef unsigned short ushort_t;

__device__ __forceinline__ float relu_f(float v) { return v > 0.f ? v : 0.f; }

__device__ __forceinline__ unsigned bf16_rne(float f) {
    unsigned u = __float_as_uint(f);
    return (u + 0x7FFFu + ((u >> 16) & 1u)) >> 16;
}
__device__ __forceinline__ float bflo(unsigned u) { return __uint_as_float(u << 16); }
__device__ __forceinline__ float bfhi(unsigned u) { return __uint_as_float(u & 0xFFFF0000u); }

// eah pair-interleaved layout: edges (2k,2k+1) share a 128B block, q-major.
// uint2 slot for (pos, lane q): (pos>>1)*16 + q*2 + (pos&1)
__device__ __forceinline__ size_t eah_u2(int pos, int q) {
    return (size_t)((unsigned)pos >> 1) * 16 + q * 2 + (pos & 1);
}

// ============================ preprocessing =============================
__global__ void __launch_bounds__(256) hist_kernel(
    const int* __restrict__ dst, int* __restrict__ deg, int E)
{
    int e = blockIdx.x * 256 + threadIdx.x;
    if (e < E) atomicAdd(&deg[dst[e]], 1);
}

__global__ void __launch_bounds__(256) scan_partial_kernel(
    const int* __restrict__ deg, int* __restrict__ part, int N)
{
    __shared__ int s[256];
    int t = threadIdx.x;
    int base = blockIdx.x * SCAN_CHUNK + t * 4;
    int sum = 0;
    #pragma unroll
    for (int i = 0; i < 4; ++i) { int idx = base + i; if (idx < N) sum += deg[idx]; }
    s[t] = sum;
    __syncthreads();
    for (int off = 128; off > 0; off >>= 1) {
        if (t < off) s[t] += s[t + off];
        __syncthreads();
    }
    if (t == 0) part[blockIdx.x] = s[0];
}

__global__ void scan_part_exclusive_kernel(int* part, int nb)
{
    if (threadIdx.x == 0 && blockIdx.x == 0) {
        int run = 0;
        for (int i = 0; i < nb; ++i) { int v = part[i]; part[i] = run; run += v; }
    }
}

__global__ void __launch_bounds__(256) scan_final_kernel(
    int* __restrict__ rowdeg, const int* __restrict__ part, int N)
{
    __shared__ int s[256];
    int t = threadIdx.x;
    int base = blockIdx.x * SCAN_CHUNK + t * 4;
    int d0 = 0, d1 = 0, d2 = 0, d3 = 0;
    if (base + 0 < N) d0 = rowdeg[base + 0];
    if (base + 1 < N) d1 = rowdeg[base + 1];
    if (base + 2 < N) d2 = rowdeg[base + 2];
    if (base + 3 < N) d3 = rowdeg[base + 3];
    int tsum = d0 + d1 + d2 + d3;
    s[t] = tsum;
    __syncthreads();
    for (int off = 1; off < 256; off <<= 1) {
        int a = (t >= off) ? s[t - off] : 0;
        __syncthreads();
        s[t] += a;
        __syncthreads();
    }
    int excl = s[t] - tsum + part[blockIdx.x];
    if (base + 0 < N) rowdeg[base + 0] = excl;
    if (base + 1 < N) rowdeg[base + 1] = excl + d0;
    if (base + 2 < N) rowdeg[base + 2] = excl + d0 + d1;
    if (base + 3 < N) rowdeg[base + 3] = excl + d0 + d1 + d2;
}

// 8 threads/edge; lane 0 claims slot (row[] exclusive -> inclusive) + writes
// packed src|dstlocal; ea row converted to bf16, written to its sorted slot
// in PAIR-INTERLEAVED layout. Nontemporal hints on scalar-typed pointers
// only (builtin rejects HIP vector types).
__global__ void __launch_bounds__(256) place_full_kernel(
    const int* __restrict__ src, const int* __restrict__ dst,
    const float* __restrict__ ea, int* __restrict__ row,
    int* __restrict__ srcpk, uint2* __restrict__ eah, int E)
{
    int i = blockIdx.x * 256 + threadIdx.x;
    if (i >= E * 8) return;
    int e = i >> 3, q = i & 7;
    int pos = 0;
    if (q == 0) {
        int d = dst[e];
        pos = atomicAdd(&row[d], 1);
        __builtin_nontemporal_store(src[e] | ((d & (NPB - 1)) << SRC_BITS), &srcpk[pos]);
    }
    pos = __shfl(pos, 0, 8);
    const float* eap = ea + ((size_t)e * 8 + q) * 4;
    float vx = __builtin_nontemporal_load(eap + 0);
    float vy = __builtin_nontemporal_load(eap + 1);
    float vz = __builtin_nontemporal_load(eap + 2);
    float vw = __builtin_nontemporal_load(eap + 3);
    unsigned long long w =
        (unsigned long long)(bf16_rne(vx) | (bf16_rne(vy) << 16)) |
        ((unsigned long long)(bf16_rne(vz) | (bf16_rne(vw) << 16)) << 32);
    __builtin_nontemporal_store(
        w, reinterpret_cast<unsigned long long*>(eah + eah_u2(pos, q)));
}

__global__ void __launch_bounds__(256) place_csr_kernel(
    const int* __restrict__ src, const int* __restrict__ dst,
    int* __restrict__ row, int* __restrict__ srcperm,
    int* __restrict__ eperm, int E)
{
    int e = blockIdx.x * 256 + threadIdx.x;
    if (e < E) {
        int pos = atomicAdd(&row[dst[e]], 1);
        srcperm[pos] = src[e] | ((dst[e] & (NPB - 1)) << SRC_BITS);
        eperm[pos] = e;
    }
}

// fp32 -> bf16 node features (once per call)
__global__ void __launch_bounds__(256) x2h_kernel(
    const float* __restrict__ x, ushort_t* __restrict__ xh, int n)
{
    int i = blockIdx.x * 256 + threadIdx.x;
    if (i < n) xh[i] = (ushort_t)bf16_rne(x[i]);
}

// ========================= fused layer (v8) ============================
// R7/R8 structure (32x 8-lane groups, LDS srcpk, register double-buffer,
// segmented accumulation, LDS-atomic flush, in-block MLP). eah now read as
// EDGE-PAIRS: one uint4/lane = 128B full line per group per 2 edges ->
// HBM requests/edge 2.0 -> 1.5, eah half becomes 128B sequential streams.
template <bool LAST>
__global__ void __launch_bounds__(256, 4) gine_fused8_kernel(
    const uint2* __restrict__ xh2,        // bf16 node rows (8 uint2 each)
    const uint2* __restrict__ eah,        // pair-interleaved bf16 edge rows
    const int* __restrict__ srcpk, const int* __restrict__ row,
    const float* __restrict__ W1, const float* __restrict__ b1,
    const float* __restrict__ W2, const float* __restrict__ b2,
    const float* __restrict__ eps, int l,
    ushort_t* __restrict__ outh, float* __restrict__ outf, int N)
{
    __shared__ float aggr[NPB][D];          // 8KB
    __shared__ float W1s[D * D], W2s[D * D];
    __shared__ float b1s[D], b2s[D];
    __shared__ float ys[8][D];
    __shared__ int   pkL[PKCAP];            // 8KB

    const uint4* eah4 = reinterpret_cast<const uint4*>(eah);

    int t = threadIdx.x;
    int n0 = blockIdx.x * NPB;
    int nlast = min(n0 + NPB - 1, N - 1);
    int estart = n0 ? row[n0 - 1] : 0;      // row[] is inclusive prefix
    int eend   = row[nlast];
    int EB = eend - estart;
    int staged = min(EB, PKCAP);

    for (int i = t; i < D * D; i += 256) { W1s[i] = W1[i]; W2s[i] = W2[i]; }
    if (t < D) { b1s[t] = b1[t]; b2s[t] = b2[t]; }
    for (int i = t; i < NPB * D; i += 256) ((float*)aggr)[i] = 0.f;
    for (int i = t; i < staged; i += 256) pkL[i] = srcpk[estart + i];
    __syncthreads();

    int g8 = t >> 3;                        // group 0..31
    int q  = t & 7;                         // lane in group; owns features 4q..4q+3

    int chunk = (staged + 31) >> 5;
    int a = min(g8 * chunk, staged);        // LOCAL staged index
    int b = min(a + chunk, staged);

    float4 acc = make_float4(0.f, 0.f, 0.f, 0.f);
    int cur = -1;

    auto flush = [&]() {
        if (cur >= 0) {
            atomicAdd(&aggr[cur][q * 4 + 0], acc.x);
            atomicAdd(&aggr[cur][q * 4 + 1], acc.y);
            atomicAdd(&aggr[cur][q * 4 + 2], acc.z);
            atomicAdd(&aggr[cur][q * 4 + 3], acc.w);
        }
    };
    auto edge = [&](int ld, uint2 ew, uint2 xw) {
        if (ld != cur) {
            flush();
            cur = ld;
            acc = make_float4(0.f, 0.f, 0.f, 0.f);
        }
        acc.x += relu_f(bflo(xw.x) + bflo(ew.x));
        acc.y += relu_f(bfhi(xw.x) + bfhi(ew.x));
        acc.z += relu_f(bflo(xw.y) + bflo(ew.y));
        acc.w += relu_f(bfhi(xw.y) + bfhi(ew.y));
    };
    // single-edge path (odd heads/tails): LOCAL index e
    auto single = [&](int e, int pk) {
        uint2 w = eah[eah_u2(estart + e, q)];
        uint2 xw = xh2[(size_t)(pk & SRC_MASK) * 8 + q];
        edge((pk >> SRC_BITS) & (NPB - 1), w, xw);
    };

    uint4 eA[2], eB[2];
    uint2 xA[4], xB[4];
    int   pA[4], pB[4];

    // base = LOCAL staged index of 4-edge (2-pair) batch; estart+base is EVEN
    auto loadA = [&](int base) {
        int gp = estart + base;
        eA[0] = eah4[((size_t)((unsigned)gp >> 1)) * 8 + q];
        eA[1] = eah4[((size_t)((unsigned)(gp + 2) >> 1)) * 8 + q];
        #pragma unroll
        for (int i = 0; i < 4; ++i) {
            int p = pkL[base + i];           // LDS broadcast within group
            pA[i] = p;
            xA[i] = xh2[(size_t)(p & SRC_MASK) * 8 + q];
        }
    };
    auto loadB = [&](int base) {
        int gp = estart + base;
        eB[0] = eah4[((size_t)((unsigned)gp >> 1)) * 8 + q];
        eB[1] = eah4[((size_t)((unsigned)(gp + 2) >> 1)) * 8 + q];
        #pragma unroll
        for (int i = 0; i < 4; ++i) {
            int p = pkL[base + i];
            pB[i] = p;
            xB[i] = xh2[(size_t)(p & SRC_MASK) * 8 + q];
        }
    };
    auto computeA = [&]() {
        edge((pA[0] >> SRC_BITS) & (NPB - 1), make_uint2(eA[0].x, eA[0].y), xA[0]);
        edge((pA[1] >> SRC_BITS) & (NPB - 1), make_uint2(eA[0].z, eA[0].w), xA[1]);
        edge((pA[2] >> SRC_BITS) & (NPB - 1), make_uint2(eA[1].x, eA[1].y), xA[2]);
        edge((pA[3] >> SRC_BITS) & (NPB - 1), make_uint2(eA[1].z, eA[1].w), xA[3]);
    };
    auto computeB = [&]() {
        edge((pB[0] >> SRC_BITS) & (NPB - 1), make_uint2(eB[0].x, eB[0].y), xB[0]);
        edge((pB[1] >> SRC_BITS) & (NPB - 1), make_uint2(eB[0].z, eB[0].w), xB[1]);
        edge((pB[2] >> SRC_BITS) & (NPB - 1), make_uint2(eB[1].x, eB[1].y), xB[2]);
        edge((pB[3] >> SRC_BITS) & (NPB - 1), make_uint2(eB[1].z, eB[1].w), xB[3]);
    };

    int k = a;
    if (k < b && ((estart + k) & 1)) {       // peel odd head -> pairs aligned
        single(k, pkL[k]);
        ++k;
    }
    int nfull = (b - k) >> 2;               // full 4-edge (2-pair) batches
    if (nfull > 0) loadA(k);
    int i = 0;
    for (; i + 2 <= nfull; i += 2) {
        loadB(k + 4);
        computeA();
        if (i + 2 < nfull) loadA(k + 8);
        computeB();
        k += 8;
    }
    if (i < nfull) { computeA(); k += 4; }

    for (int e = k; e < b; ++e) single(e, pkL[e]);   // tail (<4 edges)

    if (EB > staged) {                       // overflow: never for this input
        int ovn = EB - staged;
        int c2 = (ovn + 31) >> 5;
        int o0 = staged + min(g8 * c2, ovn);
        int o1 = min(o0 + c2, EB);
        for (int e = o0; e < o1; ++e) single(e, srcpk[estart + e]);
    }
    flush();
    __syncthreads();

    // -------- MLP: half-wave hw owns nodes hw*8 .. hw*8+7 --------
    const ushort_t* xhu = (const ushort_t*)xh2;
    int hw = t >> 5, j = t & 31;
    float ep1 = 1.0f + eps[l];
    for (int r = 0; r < 8; ++r) {
        int ln = hw * 8 + r;
        int n = n0 + ln;
        if (n >= N) break;                  // no barriers below: safe
        float xf = bflo((unsigned)xhu[(size_t)n * D + j]);
        float h = ep1 * xf + aggr[ln][j];
        aggr[ln][j] = h;                    // stage for broadcast reads
        float a1 = b1s[j];
        #pragma unroll
        for (int kk = 0; kk < D; ++kk)
            a1 = fmaf(aggr[ln][kk], W1s[kk * D + j], a1);
        float y = relu_f(a1);
        ys[hw][j] = y;
        float a2 = b2s[j];
        #pragma unroll
        for (int kk = 0; kk < D; ++kk)
            a2 = fmaf(ys[hw][kk], W2s[kk * D + j], a2);
        float o = relu_f(a2);
        if (LAST) outf[(size_t)n * D + j] = o;
        else      outh[(size_t)n * D + j] = (ushort_t)bf16_rne(o);
    }
}

// ================= fallback fused kernel (CSR gather path) =============
__global__ void __launch_bounds__(256) gine_fused_kernel(
    const float* __restrict__ x, const float* __restrict__ ea,
    const int* __restrict__ srcperm, const int* __restrict__ eperm,
    const int* __restrict__ row,
    const float* __restrict__ W1, const float* __restrict__ b1,
    const float* __restrict__ W2, const float* __restrict__ b2,
    const float* __restrict__ eps, int l, float* __restrict__ out, int N)
{
    __shared__ float W1s[D * D], W2s[D * D], b1s[D], b2s[D];
    int t = threadIdx.x;
    for (int i = t; i < D * D; i += 256) { W1s[i] = W1[i]; W2s[i] = W2[i]; }
    if (t < D) { b1s[t] = b1[t]; b2s[t] = b2[t]; }
    __syncthreads();

    int g = t >> 5, j = t & 31;
    int node = blockIdx.x * 8 + g;
    if (node >= N) return;
    int start = node ? row[node - 1] : 0;
    int end = row[node];

    float acc = 0.f;
    for (int k = start; k < end; ++k) {
        int s0 = srcperm[k] & SRC_MASK;
        float e0 = ea[(size_t)eperm[k] * D + j];
        acc += relu_f(x[(size_t)s0 * D + j] + e0);
    }
    float h = (1.0f + eps[l]) * x[(size_t)node * D + j] + acc;
    float a1 = b1s[j];
    #pragma unroll
    for (int kk = 0; kk < D; ++kk)
        a1 = fmaf(__shfl(h, kk, 32), W1s[kk * D + j], a1);
    float y = relu_f(a1);
    float a2 = b2s[j];
    #pragma unroll
    for (int kk = 0; kk < D; ++kk)
        a2 = fmaf(__shfl(y, kk, 32), W2s[kk * D + j], a2);
    out[(size_t)node * D + j] = relu_f(a2);
}

// ===================== atomic fallback path ====================
__global__ void __launch_bounds__(256) gine_scatter_kernel(
    const float* __restrict__ x, const float* __restrict__ ea,
    const int* __restrict__ src, const int* __restrict__ dst,
    float* __restrict__ aggr, int E)
{
    int i = blockIdx.x * blockDim.x + threadIdx.x;
    if (i >= E * 8) return;
    int e = i >> 3, q = i & 7;
    float4 a = reinterpret_cast<const float4*>(ea)[(size_t)e * 8 + q];
    int s = src[e], d = dst[e];
    float4 xv = reinterpret_cast<const float4*>(x)[(size_t)s * 8 + q];
    float* base = aggr + (size_t)d * D + (size_t)q * 4;
    __hip_atomic_fetch_add(base + 0, relu_f(xv.x + a.x), __ATOMIC_RELAXED, __HIP_MEMORY_SCOPE_AGENT);
    __hip_atomic_fetch_add(base + 1, relu_f(xv.y + a.y), __ATOMIC_RELAXED, __HIP_MEMORY_SCOPE_AGENT);
    __hip_atomic_fetch_add(base + 2, relu_f(xv.z + a.z), __ATOMIC_RELAXED, __HIP_MEMORY_SCOPE_AGENT);
    __hip_atomic_fetch_add(base + 3, relu_f(xv.w + a.w), __ATOMIC_RELAXED, __HIP_MEMORY_SCOPE_AGENT);
}

__global__ void __launch_bounds__(256) gine_node_kernel(
    const float* __restrict__ x, const float* __restrict__ aggr,
    const float* __restrict__ W1, const float* __restrict__ b1,
    const float* __restrict__ W2, const float* __restrict__ b2,
    const float* __restrict__ eps, int l, float* __restrict__ out, int N)
{
    __shared__ float W1s[D * D], W2s[D * D], b1s[D], b2s[D];
    __shared__ float hs[8][D], y1s[8][D];
    int t = threadIdx.x;
    for (int i = t; i < D * D; i += 256) { W1s[i] = W1[i]; W2s[i] = W2[i]; }
    if (t < D) { b1s[t] = b1[t]; b2s[t] = b2[t]; }
    float ep1 = 1.0f + eps[l];
    int local = t >> 5, j = t & 31;
    int node = blockIdx.x * 8 + local;
    __syncthreads();
    if (node < N)
        hs[local][j] = ep1 * x[(size_t)node * D + j] + aggr[(size_t)node * D + j];
    __syncthreads();
    if (node < N) {
        float acc = b1s[j];
        #pragma unroll
        for (int k = 0; k < D; ++k) acc = fmaf(hs[local][k], W1s[k * D + j], acc);
        y1s[local][j] = relu_f(acc);
    }
    __syncthreads();
    if (node < N) {
        float acc = b2s[j];
        #pragma unroll
        for (int k = 0; k < D; ++k) acc = fmaf(y1s[local][k], W2s[k * D + j], acc);
        out[(size_t)node * D + j] = relu_f(acc);
    }
}

// ============================== launcher ===============================
extern "C" void kernel_launch(void* const* d_in, const int* in_sizes, int n_in,
                              void* d_out, int out_size, void* d_ws, size_t ws_size,
                              hipStream_t stream) {
    const float* x_in = (const float*)d_in[0];
    const float* ea   = (const float*)d_in[1];
    const int*   ei   = (const int*)d_in[2];
    const float* W1   = (const float*)d_in[3];
    const float* b1   = (const float*)d_in[4];
    const float* W2   = (const float*)d_in[5];
    const float* b2   = (const float*)d_in[6];
    const float* eps  = (const float*)d_in[7];

    int N = in_sizes[0] / D;
    int E = in_sizes[1] / D;
    int L = in_sizes[3] / (D * D);

    const int* src = ei;       // edge_index[0] = message source j
    const int* dst = ei + E;   // edge_index[1] = message target i

    float* out = (float*)d_out;
    char*  ws  = (char*)d_ws;

    size_t off = 0;
    auto take = [&](size_t bytes) -> size_t {
        size_t p = off; off = (off + bytes + 255) & ~(size_t)255; return p;
    };
    size_t o_bufA    = take((size_t)N * D * sizeof(float));
    size_t o_row     = take((size_t)(N + 8) * sizeof(int));
    size_t o_part    = take(1024 * sizeof(int));
    size_t o_srcpk   = take((size_t)E * sizeof(int));
    size_t o_eperm   = take((size_t)E * sizeof(int));
    size_t need_csr  = off;
    size_t o_eah     = take((((size_t)E + 1) / 2) * 128);   // pair-interleaved bf16
    size_t o_xhA     = take((size_t)N * D * sizeof(ushort_t));
    size_t o_xhB     = take((size_t)N * D * sizeof(ushort_t));
    size_t need_full = off;

    float* bufA  = (float*)(ws + o_bufA);
    int*   row   = (int*)(ws + o_row);
    int*   part  = (int*)(ws + o_part);
    int*   srcpk = (int*)(ws + o_srcpk);
    int*   eperm = (int*)(ws + o_eperm);

    int path = (ws_size >= need_full) ? 3 : (ws_size >= need_csr ? 1 : 0);

    if (path == 0) {
        float* aggr = bufA + (size_t)N * D;   // legacy path (needs 2*N*D)
        const float* cur = x_in;
        for (int l = 0; l < L; ++l) {
            float* nxt = (((L - 1 - l) & 1) == 0) ? out : bufA;
            hipMemsetAsync(aggr, 0, (size_t)N * D * sizeof(float), stream);
            gine_scatter_kernel<<<(E * 8 + 255) / 256, 256, 0, stream>>>(cur, ea, src, dst, aggr, E);
            gine_node_kernel<<<(N + 7) / 8, 256, 0, stream>>>(
                cur, aggr, W1 + (size_t)l * D * D, b1 + (size_t)l * D,
                W2 + (size_t)l * D * D, b2 + (size_t)l * D, eps, l, nxt, N);
            cur = nxt;
        }
        return;
    }

    // ---- preprocessing (once per call) ----
    int nb = (N + SCAN_CHUNK - 1) / SCAN_CHUNK;
    hipMemsetAsync(row, 0, (size_t)N * sizeof(int), stream);
    hist_kernel<<<(E + 255) / 256, 256, 0, stream>>>(dst, row, E);
    scan_partial_kernel<<<nb, 256, 0, stream>>>(row, part, N);
    scan_part_exclusive_kernel<<<1, 64, 0, stream>>>(part, nb);
    scan_final_kernel<<<nb, 256, 0, stream>>>(row, part, N);

    if (path == 3) {
        uint2*    eah = (uint2*)(ws + o_eah);
        ushort_t* xhA = (ushort_t*)(ws + o_xhA);
        ushort_t* xhB = (ushort_t*)(ws + o_xhB);

        place_full_kernel<<<(E * 8 + 255) / 256, 256, 0, stream>>>(
            src, dst, ea, row, srcpk, eah, E);
        // row[n] is now the inclusive prefix (end offset of node n)
        x2h_kernel<<<(N * D + 255) / 256, 256, 0, stream>>>(x_in, xhA, N * D);

        ushort_t* curh = xhA;
        ushort_t* nxth = xhB;
        int nblk = (N + NPB - 1) / NPB;
        for (int l = 0; l < L; ++l) {
            if (l == L - 1) {
                gine_fused8_kernel<true><<<nblk, 256, 0, stream>>>(
                    (const uint2*)curh, eah, srcpk, row,
                    W1 + (size_t)l * D * D, b1 + (size_t)l * D,
                    W2 + (size_t)l * D * D, b2 + (size_t)l * D, eps, l,
                    nullptr, out, N);
            } else {
                gine_fused8_kernel<false><<<nblk, 256, 0, stream>>>(
                    (const uint2*)curh, eah, srcpk, row,
                    W1 + (size_t)l * D * D, b1 + (size_t)l * D,
                    W2 + (size_t)l * D * D, b2 + (size_t)l * D, eps, l,
                    nxth, nullptr, N);
                ushort_t* tmp = curh; curh = nxth; nxth = tmp;
            }
        }
        return;
    }

    // path 1: CSR fallback (fp32 gather fused layers)
    place_csr_kernel<<<(E + 255) / 256, 256, 0, stream>>>(
        src, dst, row, srcpk, eperm, E);
    const float* cur = x_in;
    for (int l = 0; l < L; ++l) {
        float* nxt = (((L - 1 - l) & 1) == 0) ? out : bufA;
        gine_fused_kernel<<<(N + 7) / 8, 256, 0, stream>>>(
            cur, ea, srcpk, eperm, row,
            W1 + (size_t)l * D * D, b1 + (size_t)l * D,
            W2 + (size_t)l * D * D, b2 + (size_t)l * D, eps, l, nxt, N);
        cur = nxt;
    }
}

// Round 11
// 514.800 us; speedup vs baseline: 1.1178x; 1.1178x over previous
//
#include <hip/hip_runtime.h>

#define D 32
#define NPB 64                      // nodes per fused block (dst-local fits 6 bits)
#define SRC_BITS 25
#define SRC_MASK ((1 << SRC_BITS) - 1)
#define SCAN_CHUNK 1024
#define PKCAP 2048                  // staged srcpk per block (mean EB=1024)

typedef unsigned short ushort_t;

__device__ __forceinline__ float relu_f(float v) { return v > 0.f ? v : 0.f; }

__device__ __forceinline__ unsigned bf16_rne(float f) {
    unsigned u = __float_as_uint(f);
    return (u + 0x7FFFu + ((u >> 16) & 1u)) >> 16;
}
__device__ __forceinline__ float bflo(unsigned u) { return __uint_as_float(u << 16); }
__device__ __forceinline__ float bfhi(unsigned u) { return __uint_as_float(u & 0xFFFF0000u); }

// ============================ preprocessing =============================
__global__ void __launch_bounds__(256) hist_kernel(
    const int* __restrict__ dst, int* __restrict__ deg, int E)
{
    int e = blockIdx.x * 256 + threadIdx.x;
    if (e < E) atomicAdd(&deg[dst[e]], 1);
}

__global__ void __launch_bounds__(256) scan_partial_kernel(
    const int* __restrict__ deg, int* __restrict__ part, int N)
{
    __shared__ int s[256];
    int t = threadIdx.x;
    int base = blockIdx.x * SCAN_CHUNK + t * 4;
    int sum = 0;
    #pragma unroll
    for (int i = 0; i < 4; ++i) { int idx = base + i; if (idx < N) sum += deg[idx]; }
    s[t] = sum;
    __syncthreads();
    for (int off = 128; off > 0; off >>= 1) {
        if (t < off) s[t] += s[t + off];
        __syncthreads();
    }
    if (t == 0) part[blockIdx.x] = s[0];
}

__global__ void scan_part_exclusive_kernel(int* part, int nb)
{
    if (threadIdx.x == 0 && blockIdx.x == 0) {
        int run = 0;
        for (int i = 0; i < nb; ++i) { int v = part[i]; part[i] = run; run += v; }
    }
}

__global__ void __launch_bounds__(256) scan_final_kernel(
    int* __restrict__ rowdeg, const int* __restrict__ part, int N)
{
    __shared__ int s[256];
    int t = threadIdx.x;
    int base = blockIdx.x * SCAN_CHUNK + t * 4;
    int d0 = 0, d1 = 0, d2 = 0, d3 = 0;
    if (base + 0 < N) d0 = rowdeg[base + 0];
    if (base + 1 < N) d1 = rowdeg[base + 1];
    if (base + 2 < N) d2 = rowdeg[base + 2];
    if (base + 3 < N) d3 = rowdeg[base + 3];
    int tsum = d0 + d1 + d2 + d3;
    s[t] = tsum;
    __syncthreads();
    for (int off = 1; off < 256; off <<= 1) {
        int a = (t >= off) ? s[t - off] : 0;
        __syncthreads();
        s[t] += a;
        __syncthreads();
    }
    int excl = s[t] - tsum + part[blockIdx.x];
    if (base + 0 < N) rowdeg[base + 0] = excl;
    if (base + 1 < N) rowdeg[base + 1] = excl + d0;
    if (base + 2 < N) rowdeg[base + 2] = excl + d0 + d1;
    if (base + 3 < N) rowdeg[base + 3] = excl + d0 + d1 + d2;
}

// 8 threads/edge; lane 0 claims slot (row[] exclusive -> inclusive) + writes
// packed src|dstlocal; ea row converted to bf16, written to sorted slot
// (uint2 index pos*8+q). NOTE: no nontemporal hints — R10 showed nt stores
// bypass L2 write-combining and INCREASE write amplification (202->300MB).
__global__ void __launch_bounds__(256) place_full_kernel(
    const int* __restrict__ src, const int* __restrict__ dst,
    const float* __restrict__ ea, int* __restrict__ row,
    int* __restrict__ srcpk, unsigned* __restrict__ eah, int E)
{
    int i = blockIdx.x * 256 + threadIdx.x;
    if (i >= E * 8) return;
    int e = i >> 3, q = i & 7;
    int pos = 0;
    if (q == 0) {
        int d = dst[e];
        pos = atomicAdd(&row[d], 1);
        srcpk[pos] = src[e] | ((d & (NPB - 1)) << SRC_BITS);
    }
    pos = __shfl(pos, 0, 8);
    float4 v = reinterpret_cast<const float4*>(ea)[(size_t)e * 8 + q];
    uint2 w;
    w.x = bf16_rne(v.x) | (bf16_rne(v.y) << 16);
    w.y = bf16_rne(v.z) | (bf16_rne(v.w) << 16);
    reinterpret_cast<uint2*>(eah)[(size_t)pos * 8 + q] = w;
}

__global__ void __launch_bounds__(256) place_csr_kernel(
    const int* __restrict__ src, const int* __restrict__ dst,
    int* __restrict__ row, int* __restrict__ srcperm,
    int* __restrict__ eperm, int E)
{
    int e = blockIdx.x * 256 + threadIdx.x;
    if (e < E) {
        int pos = atomicAdd(&row[dst[e]], 1);
        srcperm[pos] = src[e] | ((dst[e] & (NPB - 1)) << SRC_BITS);
        eperm[pos] = e;
    }
}

// fp32 -> bf16 node features (once per call)
__global__ void __launch_bounds__(256) x2h_kernel(
    const float* __restrict__ x, ushort_t* __restrict__ xh, int n)
{
    int i = blockIdx.x * 256 + threadIdx.x;
    if (i < n) xh[i] = (ushort_t)bf16_rne(x[i]);
}

// ========================= fused layer (R8/v7) =========================
// 32x 8-lane groups, LDS-staged srcpk, register double-buffer, segmented
// accumulation with LDS-atomic flush, in-block MLP. Node features bf16
// between layers; accumulation and MLP fp32.
template <bool LAST>
__global__ void __launch_bounds__(256, 4) gine_fused7_kernel(
    const uint2* __restrict__ xh2,        // bf16 node rows (8 uint2 each)
    const uint2* __restrict__ eah,
    const int* __restrict__ srcpk, const int* __restrict__ row,
    const float* __restrict__ W1, const float* __restrict__ b1,
    const float* __restrict__ W2, const float* __restrict__ b2,
    const float* __restrict__ eps, int l,
    ushort_t* __restrict__ outh, float* __restrict__ outf, int N)
{
    __shared__ float aggr[NPB][D];          // 8KB
    __shared__ float W1s[D * D], W2s[D * D];
    __shared__ float b1s[D], b2s[D];
    __shared__ float ys[8][D];
    __shared__ int   pkL[PKCAP];            // 8KB

    int t = threadIdx.x;
    int n0 = blockIdx.x * NPB;
    int nlast = min(n0 + NPB - 1, N - 1);
    int estart = n0 ? row[n0 - 1] : 0;      // row[] is inclusive prefix
    int eend   = row[nlast];
    int EB = eend - estart;
    int staged = min(EB, PKCAP);

    for (int i = t; i < D * D; i += 256) { W1s[i] = W1[i]; W2s[i] = W2[i]; }
    if (t < D) { b1s[t] = b1[t]; b2s[t] = b2[t]; }
    for (int i = t; i < NPB * D; i += 256) ((float*)aggr)[i] = 0.f;
    for (int i = t; i < staged; i += 256) pkL[i] = srcpk[estart + i];
    __syncthreads();

    int g8 = t >> 3;                        // group 0..31
    int q  = t & 7;                         // lane in group; owns features 4q..4q+3

    int chunk = (staged + 31) >> 5;
    int a = min(g8 * chunk, staged);
    int b = min(a + chunk, staged);

    float4 acc = make_float4(0.f, 0.f, 0.f, 0.f);
    int cur = -1;

    auto flush = [&]() {
        if (cur >= 0) {
            atomicAdd(&aggr[cur][q * 4 + 0], acc.x);
            atomicAdd(&aggr[cur][q * 4 + 1], acc.y);
            atomicAdd(&aggr[cur][q * 4 + 2], acc.z);
            atomicAdd(&aggr[cur][q * 4 + 3], acc.w);
        }
    };
    auto edge = [&](int ld, uint2 ew, uint2 xw) {
        if (ld != cur) {
            flush();
            cur = ld;
            acc = make_float4(0.f, 0.f, 0.f, 0.f);
        }
        acc.x += relu_f(bflo(xw.x) + bflo(ew.x));
        acc.y += relu_f(bfhi(xw.x) + bfhi(ew.x));
        acc.z += relu_f(bflo(xw.y) + bflo(ew.y));
        acc.w += relu_f(bfhi(xw.y) + bfhi(ew.y));
    };

    uint2 wA[4], wB[4], xA[4], xB[4];
    int   pA[4], pB[4];

    auto loadA = [&](int base) {
        #pragma unroll
        for (int i = 0; i < 4; ++i) {
            int p = pkL[base + i];           // LDS broadcast within group
            pA[i] = p;
            wA[i] = eah[(size_t)(estart + base + i) * 8 + q];
            xA[i] = xh2[(size_t)(p & SRC_MASK) * 8 + q];
        }
    };
    auto loadB = [&](int base) {
        #pragma unroll
        for (int i = 0; i < 4; ++i) {
            int p = pkL[base + i];
            pB[i] = p;
            wB[i] = eah[(size_t)(estart + base + i) * 8 + q];
            xB[i] = xh2[(size_t)(p & SRC_MASK) * 8 + q];
        }
    };
    auto computeA = [&]() {
        #pragma unroll
        for (int i = 0; i < 4; ++i)
            edge((pA[i] >> SRC_BITS) & (NPB - 1), wA[i], xA[i]);
    };
    auto computeB = [&]() {
        #pragma unroll
        for (int i = 0; i < 4; ++i)
            edge((pB[i] >> SRC_BITS) & (NPB - 1), wB[i], xB[i]);
    };

    int nfull = (b - a) >> 2;
    int k = a;
    if (nfull > 0) loadA(k);
    int i = 0;
    for (; i + 2 <= nfull; i += 2) {
        loadB(k + 4);
        computeA();
        if (i + 2 < nfull) loadA(k + 8);
        computeB();
        k += 8;
    }
    if (i < nfull) { computeA(); k += 4; }

    for (int e = k; e < b; ++e) {
        int p = pkL[e];
        uint2 w = eah[(size_t)(estart + e) * 8 + q];
        uint2 xw = xh2[(size_t)(p & SRC_MASK) * 8 + q];
        edge((p >> SRC_BITS) & (NPB - 1), w, xw);
    }
    if (EB > staged) {                       // overflow: never for this input
        int ovn = EB - staged;
        int c2 = (ovn + 31) >> 5;
        int o0 = staged + min(g8 * c2, ovn);
        int o1 = min(o0 + c2, EB);
        for (int e = o0; e < o1; ++e) {
            int p = srcpk[estart + e];
            uint2 w = eah[(size_t)(estart + e) * 8 + q];
            uint2 xw = xh2[(size_t)(p & SRC_MASK) * 8 + q];
            edge((p >> SRC_BITS) & (NPB - 1), w, xw);
        }
    }
    flush();
    __syncthreads();

    // -------- MLP: half-wave hw owns nodes hw*8 .. hw*8+7 --------
    const ushort_t* xhu = (const ushort_t*)xh2;
    int hw = t >> 5, j = t & 31;
    float ep1 = 1.0f + eps[l];
    for (int r = 0; r < 8; ++r) {
        int ln = hw * 8 + r;
        int n = n0 + ln;
        if (n >= N) break;                  // no barriers below: safe
        float xf = bflo((unsigned)xhu[(size_t)n * D + j]);
        float h = ep1 * xf + aggr[ln][j];
        aggr[ln][j] = h;                    // stage for broadcast reads
        float a1 = b1s[j];
        #pragma unroll
        for (int kk = 0; kk < D; ++kk)
            a1 = fmaf(aggr[ln][kk], W1s[kk * D + j], a1);
        float y = relu_f(a1);
        ys[hw][j] = y;
        float a2 = b2s[j];
        #pragma unroll
        for (int kk = 0; kk < D; ++kk)
            a2 = fmaf(ys[hw][kk], W2s[kk * D + j], a2);
        float o = relu_f(a2);
        if (LAST) outf[(size_t)n * D + j] = o;
        else      outh[(size_t)n * D + j] = (ushort_t)bf16_rne(o);
    }
}

// ================= fallback fused kernel (CSR gather path) =============
__global__ void __launch_bounds__(256) gine_fused_kernel(
    const float* __restrict__ x, const float* __restrict__ ea,
    const int* __restrict__ srcperm, const int* __restrict__ eperm,
    const int* __restrict__ row,
    const float* __restrict__ W1, const float* __restrict__ b1,
    const float* __restrict__ W2, const float* __restrict__ b2,
    const float* __restrict__ eps, int l, float* __restrict__ out, int N)
{
    __shared__ float W1s[D * D], W2s[D * D], b1s[D], b2s[D];
    int t = threadIdx.x;
    for (int i = t; i < D * D; i += 256) { W1s[i] = W1[i]; W2s[i] = W2[i]; }
    if (t < D) { b1s[t] = b1[t]; b2s[t] = b2[t]; }
    __syncthreads();

    int g = t >> 5, j = t & 31;
    int node = blockIdx.x * 8 + g;
    if (node >= N) return;
    int start = node ? row[node - 1] : 0;
    int end = row[node];

    float acc = 0.f;
    for (int k = start; k < end; ++k) {
        int s0 = srcperm[k] & SRC_MASK;
        float e0 = ea[(size_t)eperm[k] * D + j];
        acc += relu_f(x[(size_t)s0 * D + j] + e0);
    }
    float h = (1.0f + eps[l]) * x[(size_t)node * D + j] + acc;
    float a1 = b1s[j];
    #pragma unroll
    for (int kk = 0; kk < D; ++kk)
        a1 = fmaf(__shfl(h, kk, 32), W1s[kk * D + j], a1);
    float y = relu_f(a1);
    float a2 = b2s[j];
    #pragma unroll
    for (int kk = 0; kk < D; ++kk)
        a2 = fmaf(__shfl(y, kk, 32), W2s[kk * D + j], a2);
    out[(size_t)node * D + j] = relu_f(a2);
}

// ===================== atomic fallback path ====================
__global__ void __launch_bounds__(256) gine_scatter_kernel(
    const float* __restrict__ x, const float* __restrict__ ea,
    const int* __restrict__ src, const int* __restrict__ dst,
    float* __restrict__ aggr, int E)
{
    int i = blockIdx.x * blockDim.x + threadIdx.x;
    if (i >= E * 8) return;
    int e = i >> 3, q = i & 7;
    float4 a = reinterpret_cast<const float4*>(ea)[(size_t)e * 8 + q];
    int s = src[e], d = dst[e];
    float4 xv = reinterpret_cast<const float4*>(x)[(size_t)s * 8 + q];
    float* base = aggr + (size_t)d * D + (size_t)q * 4;
    __hip_atomic_fetch_add(base + 0, relu_f(xv.x + a.x), __ATOMIC_RELAXED, __HIP_MEMORY_SCOPE_AGENT);
    __hip_atomic_fetch_add(base + 1, relu_f(xv.y + a.y), __ATOMIC_RELAXED, __HIP_MEMORY_SCOPE_AGENT);
    __hip_atomic_fetch_add(base + 2, relu_f(xv.z + a.z), __ATOMIC_RELAXED, __HIP_MEMORY_SCOPE_AGENT);
    __hip_atomic_fetch_add(base + 3, relu_f(xv.w + a.w), __ATOMIC_RELAXED, __HIP_MEMORY_SCOPE_AGENT);
}

__global__ void __launch_bounds__(256) gine_node_kernel(
    const float* __restrict__ x, const float* __restrict__ aggr,
    const float* __restrict__ W1, const float* __restrict__ b1,
    const float* __restrict__ W2, const float* __restrict__ b2,
    const float* __restrict__ eps, int l, float* __restrict__ out, int N)
{
    __shared__ float W1s[D * D], W2s[D * D], b1s[D], b2s[D];
    __shared__ float hs[8][D], y1s[8][D];
    int t = threadIdx.x;
    for (int i = t; i < D * D; i += 256) { W1s[i] = W1[i]; W2s[i] = W2[i]; }
    if (t < D) { b1s[t] = b1[t]; b2s[t] = b2[t]; }
    float ep1 = 1.0f + eps[l];
    int local = t >> 5, j = t & 31;
    int node = blockIdx.x * 8 + local;
    __syncthreads();
    if (node < N)
        hs[local][j] = ep1 * x[(size_t)node * D + j] + aggr[(size_t)node * D + j];
    __syncthreads();
    if (node < N) {
        float acc = b1s[j];
        #pragma unroll
        for (int k = 0; k < D; ++k) acc = fmaf(hs[local][k], W1s[k * D + j], acc);
        y1s[local][j] = relu_f(acc);
    }
    __syncthreads();
    if (node < N) {
        float acc = b2s[j];
        #pragma unroll
        for (int k = 0; k < D; ++k) acc = fmaf(y1s[local][k], W2s[k * D + j], acc);
        out[(size_t)node * D + j] = relu_f(acc);
    }
}

// ============================== launcher ===============================
extern "C" void kernel_launch(void* const* d_in, const int* in_sizes, int n_in,
                              void* d_out, int out_size, void* d_ws, size_t ws_size,
                              hipStream_t stream) {
    const float* x_in = (const float*)d_in[0];
    const float* ea   = (const float*)d_in[1];
    const int*   ei   = (const int*)d_in[2];
    const float* W1   = (const float*)d_in[3];
    const float* b1   = (const float*)d_in[4];
    const float* W2   = (const float*)d_in[5];
    const float* b2   = (const float*)d_in[6];
    const float* eps  = (const float*)d_in[7];

    int N = in_sizes[0] / D;
    int E = in_sizes[1] / D;
    int L = in_sizes[3] / (D * D);

    const int* src = ei;       // edge_index[0] = message source j
    const int* dst = ei + E;   // edge_index[1] = message target i

    float* out = (float*)d_out;
    char*  ws  = (char*)d_ws;

    size_t off = 0;
    auto take = [&](size_t bytes) -> size_t {
        size_t p = off; off = (off + bytes + 255) & ~(size_t)255; return p;
    };
    size_t o_bufA    = take((size_t)N * D * sizeof(float));
    size_t o_row     = take((size_t)(N + 8) * sizeof(int));
    size_t o_part    = take(1024 * sizeof(int));
    size_t o_srcpk   = take((size_t)E * sizeof(int));
    size_t o_eperm   = take((size_t)E * sizeof(int));
    size_t need_csr  = off;
    size_t o_eah     = take((size_t)E * D * sizeof(ushort_t));
    size_t need_full = off;
    size_t o_xhA     = take((size_t)N * D * sizeof(ushort_t));
    size_t o_xhB     = take((size_t)N * D * sizeof(ushort_t));
    size_t need_xh   = off;

    float* bufA  = (float*)(ws + o_bufA);
    int*   row   = (int*)(ws + o_row);
    int*   part  = (int*)(ws + o_part);
    int*   srcpk = (int*)(ws + o_srcpk);
    int*   eperm = (int*)(ws + o_eperm);

    int path = (ws_size >= need_xh) ? 3
             : (ws_size >= need_full) ? 2
             : (ws_size >= need_csr) ? 1 : 0;

    if (path == 0) {
        float* aggr = bufA + (size_t)N * D;   // legacy path (needs 2*N*D)
        const float* cur = x_in;
        for (int l = 0; l < L; ++l) {
            float* nxt = (((L - 1 - l) & 1) == 0) ? out : bufA;
            hipMemsetAsync(aggr, 0, (size_t)N * D * sizeof(float), stream);
            gine_scatter_kernel<<<(E * 8 + 255) / 256, 256, 0, stream>>>(cur, ea, src, dst, aggr, E);
            gine_node_kernel<<<(N + 7) / 8, 256, 0, stream>>>(
                cur, aggr, W1 + (size_t)l * D * D, b1 + (size_t)l * D,
                W2 + (size_t)l * D * D, b2 + (size_t)l * D, eps, l, nxt, N);
            cur = nxt;
        }
        return;
    }

    unsigned* eah = (unsigned*)(ws + o_eah);

    // ---- preprocessing (once per call) ----
    int nb = (N + SCAN_CHUNK - 1) / SCAN_CHUNK;
    hipMemsetAsync(row, 0, (size_t)N * sizeof(int), stream);
    hist_kernel<<<(E + 255) / 256, 256, 0, stream>>>(dst, row, E);
    scan_partial_kernel<<<nb, 256, 0, stream>>>(row, part, N);
    scan_part_exclusive_kernel<<<1, 64, 0, stream>>>(part, nb);
    scan_final_kernel<<<nb, 256, 0, stream>>>(row, part, N);
    if (path >= 2) {
        place_full_kernel<<<(E * 8 + 255) / 256, 256, 0, stream>>>(
            src, dst, ea, row, srcpk, eah, E);
    } else {
        place_csr_kernel<<<(E + 255) / 256, 256, 0, stream>>>(
            src, dst, row, srcpk, eperm, E);
    }
    // row[n] is now the inclusive prefix (end offset of node n)

    if (path == 3) {
        ushort_t* xhA = (ushort_t*)(ws + o_xhA);
        ushort_t* xhB = (ushort_t*)(ws + o_xhB);
        x2h_kernel<<<(N * D + 255) / 256, 256, 0, stream>>>(x_in, xhA, N * D);

        ushort_t* curh = xhA;
        ushort_t* nxth = xhB;
        int nblk = (N + NPB - 1) / NPB;
        for (int l = 0; l < L; ++l) {
            bool last = (l == L - 1);
            if (last) {
                gine_fused7_kernel<true><<<nblk, 256, 0, stream>>>(
                    (const uint2*)curh, (const uint2*)eah, srcpk, row,
                    W1 + (size_t)l * D * D, b1 + (size_t)l * D,
                    W2 + (size_t)l * D * D, b2 + (size_t)l * D, eps, l,
                    nullptr, out, N);
            } else {
                gine_fused7_kernel<false><<<nblk, 256, 0, stream>>>(
                    (const uint2*)curh, (const uint2*)eah, srcpk, row,
                    W1 + (size_t)l * D * D, b1 + (size_t)l * D,
                    W2 + (size_t)l * D * D, b2 + (size_t)l * D, eps, l,
                    nxth, nullptr, N);
                ushort_t* tmp = curh; curh = nxth; nxth = tmp;
            }
        }
        return;
    }

    // path 1/2 fallback: fp32 CSR-gather fused layers
    const float* cur = x_in;
    for (int l = 0; l < L; ++l) {
        float* nxt = (((L - 1 - l) & 1) == 0) ? out : bufA;
        gine_fused_kernel<<<(N + 7) / 8, 256, 0, stream>>>(
            cur, ea, srcpk, eperm, row,
            W1 + (size_t)l * D * D, b1 + (size_t)l * D,
            W2 + (size_t)l * D * D, b2 + (size_t)l * D, eps, l, nxt, N);
        cur = nxt;
    }
}